// Round 7
// baseline (10661.290 us; speedup 1.0000x reference)
//
#include <hip/hip_runtime.h>
#include <math.h>
#include <stdint.h>

// Problem constants
constexpr int LL = 4096;   // seq len
constexpr int EE = 300;    // embedding dim
constexpr int HH = 256;    // per-direction hidden (H2)
constexpr int NGATE = 1024;// 4*HH
constexpr int TT = 16;     // tagset
constexpr float NEGV = -10000.0f;

typedef _Float16 v2h __attribute__((ext_vector_type(2)));
typedef _Float16 v8h __attribute__((ext_vector_type(8)));
typedef float v4f __attribute__((ext_vector_type(4)));

// Workspace layout (byte offsets)
constexpr size_t OFF_X    = 16384;
constexpr size_t OFF_ZX   = OFF_X    + (size_t)LL*EE*4;     // 2*L*1024 f32
constexpr size_t OFF_HALL = OFF_ZX   + (size_t)2*LL*NGATE*4;// 2*L*256 f32
constexpr size_t OFF_FE   = OFF_HALL + (size_t)2*LL*HH*4;   // L*16 f32

__device__ __forceinline__ v2h pack_h2(float x, float y) {
  return __builtin_bit_cast(v2h, __builtin_amdgcn_cvt_pkrtz(x, y));
}
__device__ __forceinline__ unsigned pack_u(float x, float y) {
  return __builtin_bit_cast(unsigned, __builtin_amdgcn_cvt_pkrtz(x, y));
}
__device__ __forceinline__ v2h u2h(unsigned u) {
  return __builtin_bit_cast(v2h, u);
}
__device__ __forceinline__ v8h make_v8h(v2h a, v2h b, v2h c, v2h d) {
  union { v2h p[4]; v8h v; } u; u.p[0]=a; u.p[1]=b; u.p[2]=c; u.p[3]=d; return u.v;
}

__device__ __forceinline__ float fsigmoid(float x) {
  return __builtin_amdgcn_rcpf(1.f + __expf(-x));
}
__device__ __forceinline__ float ftanh(float x) {
  return 1.f - 2.f * __builtin_amdgcn_rcpf(1.f + __expf(2.f * x));
}

template <int CTRL>
__device__ __forceinline__ int dpp_i(int v) {
  return __builtin_amdgcn_mov_dpp(v, CTRL, 0xF, 0xF, true);
}
template <int CTRL>
__device__ __forceinline__ float dpp_f(float v) {
  return __int_as_float(__builtin_amdgcn_mov_dpp(__float_as_int(v), CTRL, 0xF, 0xF, true));
}
__device__ __forceinline__ float bperm_f(int lane, float v) {
  return __int_as_float(__builtin_amdgcn_ds_bpermute(lane << 2, __float_as_int(v)));
}

// ---------------------------------------------------------------------------
// Kernel 1: embedding gather
// ---------------------------------------------------------------------------
__global__ void gather_x(const int* __restrict__ sent, const float* __restrict__ emb,
                         float* __restrict__ X) {
  const int i = blockIdx.x * blockDim.x + threadIdx.x;
  const int total = LL * (EE / 4);
  if (i >= total) return;
  const int row = i / (EE / 4), c4 = i % (EE / 4);
  const int v = sent[row];
  reinterpret_cast<float4*>(X)[(size_t)row * (EE / 4) + c4] =
      reinterpret_cast<const float4*>(emb + (size_t)v * EE)[c4];
}

// ---------------------------------------------------------------------------
// Kernel 2: input GEMM, GATE-TRANSPOSED store: Zx[t][unit*4+gate]
// (unchanged — validated R5/R6)
// ---------------------------------------------------------------------------
__global__ __launch_bounds__(256) void input_gemm(
    const float* __restrict__ X, const float* __restrict__ w_f,
    const float* __restrict__ b_f, const float* __restrict__ w_b,
    const float* __restrict__ b_b, float* __restrict__ ZX) {
  const int dir = blockIdx.z;
  const float* __restrict__ W  = dir ? w_b : w_f;
  const float* __restrict__ Bv = dir ? b_b : b_f;
  float* __restrict__ Z = ZX + (size_t)dir * LL * NGATE;
  __shared__ float As[32][68];
  __shared__ float Bs[32][68];
  const int m0 = blockIdx.y * 64, n0 = blockIdx.x * 64;
  const int t = threadIdx.x;
  const int tx = t & 15, ty = t >> 4;
  float acc[4][4] = {};
  for (int k0 = 0; k0 < EE; k0 += 32) {
#pragma unroll
    for (int r = 0; r < 2; ++r) {
      const int idx = t + r * 256;
      const int row = idx >> 3;
      const int kk4 = (idx & 7) << 2;
      const int k = k0 + kk4;
      float4 va = make_float4(0.f, 0.f, 0.f, 0.f), vb = va;
      if (k < EE) {
        va = *reinterpret_cast<const float4*>(X + (size_t)(m0 + row) * EE + k);
        vb = *reinterpret_cast<const float4*>(W + (size_t)(n0 + row) * EE + k);
      }
      As[kk4 + 0][row] = va.x; As[kk4 + 1][row] = va.y;
      As[kk4 + 2][row] = va.z; As[kk4 + 3][row] = va.w;
      Bs[kk4 + 0][row] = vb.x; Bs[kk4 + 1][row] = vb.y;
      Bs[kk4 + 2][row] = vb.z; Bs[kk4 + 3][row] = vb.w;
    }
    __syncthreads();
    const int kmax = (EE - k0 < 32) ? (EE - k0) : 32;
    for (int k = 0; k < kmax; ++k) {
      const float4 av = *reinterpret_cast<const float4*>(&As[k][ty << 2]);
      const float4 bv = *reinterpret_cast<const float4*>(&Bs[k][tx << 2]);
      acc[0][0] += av.x * bv.x; acc[0][1] += av.x * bv.y; acc[0][2] += av.x * bv.z; acc[0][3] += av.x * bv.w;
      acc[1][0] += av.y * bv.x; acc[1][1] += av.y * bv.y; acc[1][2] += av.y * bv.z; acc[1][3] += av.y * bv.w;
      acc[2][0] += av.z * bv.x; acc[2][1] += av.z * bv.y; acc[2][2] += av.z * bv.z; acc[2][3] += av.z * bv.w;
      acc[3][0] += av.w * bv.x; acc[3][1] += av.w * bv.y; acc[3][2] += av.w * bv.z; acc[3][3] += av.w * bv.w;
    }
    __syncthreads();
  }
#pragma unroll
  for (int i = 0; i < 4; ++i)
#pragma unroll
    for (int j = 0; j < 4; ++j) {
      const int m = m0 + (ty << 2) + i, n = n0 + (tx << 2) + j;
      Z[(size_t)m * NGATE + (((n & 255) << 2) | (n >> 8))] = acc[i][j] + Bv[n];
    }
}

// ---------------------------------------------------------------------------
// Kernel 3: persistent bidirectional LSTM recurrence — ONE WG per direction,
// HYBRID matvec inside the PROVEN register envelope.
//
// R6 post-mortem: any multi-CU split pays ~2600 cy/step of exchange latency
// (= the pipe time it saves). Single-CU only. Six-round budget law:
//   arch class <= ~100/thread is safe (R0: 64 wt + 36 work ran clean);
//   ~252 unified total is safe (R2 ran clean); >= ~130 arch or ~250+ w/
//   big VALU arrays spills (R1/R5).
// Partition (n = gate*256 + unit):
//   n in [0,256)    VALU fdot2: thread = (row r=t>>1, k-half kh=t&1),
//                   wv[64] v2h = 64 arch regs; one 0xB1 DPP pair-reduce.
//                   VALU pipe ~400 cy/step.
//   n in [256,1024) MFMA 48 tiles, 6/wave: tiles 0-3 register-resident
//                   B-frags (32 frags = 128 regs, AGPR-legal), tiles 4-5
//                   LDS-streamed (128 KB, ds_read_b128). A-frag = h
//                   replicated (R2/R6-verified); A/B share the
//                   (quadrant,slot)->k map; C/D read col=lane&15 only.
//                   MFMA pipe 384 chunks x 4.85 = 1863 cy/step (the wall).
// z and Zx gate-transposed (R4/R6-validated): gate phase = 1 float4 LDS
// read + 1 float4 global prefetch. Step ~2000-2300 cy vs 3620 (R2).
// ---------------------------------------------------------------------------
__global__ __launch_bounds__(512) __attribute__((amdgpu_waves_per_eu(2, 2)))
void recurrence(
    const float* __restrict__ whh_f, const float* __restrict__ whh_b,
    const float* __restrict__ h0, const float* __restrict__ c0,
    const float* __restrict__ ZX, float* __restrict__ HALL) {
  const int dir = blockIdx.x;
  const int t = threadIdx.x;
  const int w = t >> 6;            // wave 0..7
  const int l = t & 63;
  const int lcol = l & 15;
  const int lq = l >> 4;           // quadrant 0..3
  const int r  = t >> 1;           // VALU row 0..255
  const int kh = t & 1;            // VALU k-half
  const float* __restrict__ Whh = dir ? whh_b : whh_f;
  const float* __restrict__ Z = ZX + (size_t)dir * LL * NGATE;
  float* __restrict__ Hall = HALL + (size_t)dir * LL * HH;

  __shared__ uint4 WL[8 * 2 * 8 * 64];              // 128 KB: LDS B-frags (tiles 4,5/wave)
  __shared__ __align__(16) float zbuf4[NGATE];      // 4 KB, [unit][gate]
  __shared__ __align__(16) unsigned h16u[2 * 128];  // packed f16 h, parity dbuf

  // ---- preamble 1: VALU weights rows [0,256) -> 64 arch VGPRs ------------
  // wv[4i+m] covers k = 128*kh + 8i + 2m .. +1 of row r
  v2h wv[64];
  {
    const float* wr = Whh + (size_t)r * HH + (kh << 7);
#pragma unroll
    for (int i = 0; i < 16; ++i) {
      const float4 x = *reinterpret_cast<const float4*>(wr + 8 * i);
      const float4 y = *reinterpret_cast<const float4*>(wr + 8 * i + 4);
      wv[4 * i + 0] = pack_h2(x.x, x.y);
      wv[4 * i + 1] = pack_h2(x.z, x.w);
      wv[4 * i + 2] = pack_h2(y.x, y.y);
      wv[4 * i + 3] = pack_h2(y.z, y.w);
    }
  }

  // ---- preamble 2: reg-resident MFMA B-frags (tiles 0-3 of wave) ---------
  v8h bfr[4][8];
#pragma unroll
  for (int i = 0; i < 4; ++i)
#pragma unroll
    for (int kc = 0; kc < 8; ++kc) {
      const int n = 256 + (6 * w + i) * 16 + lcol;
      const float* wp = Whh + (size_t)n * HH + (kc << 5) + (lq << 3);
      const float4 a4 = *reinterpret_cast<const float4*>(wp);
      const float4 b4 = *reinterpret_cast<const float4*>(wp + 4);
      bfr[i][kc] = make_v8h(pack_h2(a4.x, a4.y), pack_h2(a4.z, a4.w),
                            pack_h2(b4.x, b4.y), pack_h2(b4.z, b4.w));
    }

  // ---- preamble 3: LDS-streamed MFMA B-frags (tiles 4,5 of wave) ---------
#pragma unroll
  for (int i = 0; i < 2; ++i)
#pragma unroll
    for (int kc = 0; kc < 8; ++kc) {
      const int n = 256 + (6 * w + 4 + i) * 16 + lcol;
      const float* wp = Whh + (size_t)n * HH + (kc << 5) + (lq << 3);
      const float4 a4 = *reinterpret_cast<const float4*>(wp);
      const float4 b4 = *reinterpret_cast<const float4*>(wp + 4);
      uint4 p;
      p.x = pack_u(a4.x, a4.y); p.y = pack_u(a4.z, a4.w);
      p.z = pack_u(b4.x, b4.y); p.w = pack_u(b4.z, b4.w);
      WL[(((w << 1) | i) * 8 + kc) * 64 + l] = p;
    }

  // ---- state init --------------------------------------------------------
  float c_reg = 0.f;
  if (t < 256) c_reg = c0[dir * HH + t];
  if (t < 128)
    h16u[t] = pack_u(h0[dir * HH + 2 * t], h0[dir * HH + 2 * t + 1]);

  float4 zx = make_float4(0.f, 0.f, 0.f, 0.f);
  if (t < 256) {
    const int trow0 = dir ? (LL - 1) : 0;
    zx = *reinterpret_cast<const float4*>(Z + (size_t)trow0 * NGATE + 4 * t);
  }
  __syncthreads();

  for (int s = 0; s < LL; ++s) {
    const int par = s & 1;
    const int npar = par ^ 1;
    // prefetch next step's Zx (one float4; hides under the matvec)
    float4 nzx = make_float4(0.f, 0.f, 0.f, 0.f);
    if (t < 256 && s + 1 < LL) {
      const int trow = dir ? (LL - 2 - s) : (s + 1);
      nzx = *reinterpret_cast<const float4*>(Z + (size_t)trow * NGATE + 4 * t);
    }

    const uint4* hq = reinterpret_cast<const uint4*>(&h16u[par << 7]);

    // ---- reg-MFMA tiles 0-3 (fills the matrix pipe early) ----------------
    v4f a0 = {0.f,0.f,0.f,0.f}, a1 = {0.f,0.f,0.f,0.f};
    v4f a2 = {0.f,0.f,0.f,0.f}, a3 = {0.f,0.f,0.f,0.f};
#pragma unroll
    for (int kc = 0; kc < 8; ++kc) {
      const v8h ah = __builtin_bit_cast(v8h, hq[(kc << 2) + lq]);
      a0 = __builtin_amdgcn_mfma_f32_16x16x32_f16(ah, bfr[0][kc], a0, 0, 0, 0);
      a1 = __builtin_amdgcn_mfma_f32_16x16x32_f16(ah, bfr[1][kc], a1, 0, 0, 0);
      a2 = __builtin_amdgcn_mfma_f32_16x16x32_f16(ah, bfr[2][kc], a2, 0, 0, 0);
      a3 = __builtin_amdgcn_mfma_f32_16x16x32_f16(ah, bfr[3][kc], a3, 0, 0, 0);
    }

    // ---- VALU fdot2: row r, k in [128kh, 128kh+128) (VALU pipe ∥ MFMA) ---
    float va = 0.f;
    {
      const uint4* hu = reinterpret_cast<const uint4*>(&h16u[(par << 7) + (kh << 6)]);
#pragma unroll
      for (int i = 0; i < 16; ++i) {
        const uint4 hv = hu[i];
        va = __builtin_amdgcn_fdot2(wv[4*i+0], u2h(hv.x), va, false);
        va = __builtin_amdgcn_fdot2(wv[4*i+1], u2h(hv.y), va, false);
        va = __builtin_amdgcn_fdot2(wv[4*i+2], u2h(hv.z), va, false);
        va = __builtin_amdgcn_fdot2(wv[4*i+3], u2h(hv.w), va, false);
      }
      va += dpp_f<0xB1>(va);           // pair (t, t^1): sum the two k-halves
      if (kh == 0) zbuf4[r << 2] = va; // n = r -> (u=r, gate 0)
    }

    // ---- LDS-streamed MFMA tiles 4,5 -------------------------------------
    v4f a4 = {0.f,0.f,0.f,0.f}, a5 = {0.f,0.f,0.f,0.f};
    {
      const int b0 = (((w << 1) | 0) * 8) * 64 + l;
      const int b1 = (((w << 1) | 1) * 8) * 64 + l;
#pragma unroll
      for (int kc = 0; kc < 8; ++kc) {
        const v8h ah = __builtin_bit_cast(v8h, hq[(kc << 2) + lq]);
        const uint4 w0 = WL[b0 + (kc << 6)];
        const uint4 w1 = WL[b1 + (kc << 6)];
        a4 = __builtin_amdgcn_mfma_f32_16x16x32_f16(ah, __builtin_bit_cast(v8h, w0), a4, 0, 0, 0);
        a5 = __builtin_amdgcn_mfma_f32_16x16x32_f16(ah, __builtin_bit_cast(v8h, w1), a5, 0, 0, 0);
      }
    }

    // ---- z writes (A rows replicated -> acc[0]; lq==0 lanes) -------------
    if (lq == 0) {
#pragma unroll
      for (int i = 0; i < 6; ++i) {
        const int n = 256 + (6 * w + i) * 16 + lcol;
        const float zv = (i == 0) ? a0[0] : (i == 1) ? a1[0] : (i == 2) ? a2[0]
                        : (i == 3) ? a3[0] : (i == 4) ? a4[0] : a5[0];
        zbuf4[((n & 255) << 2) | (n >> 8)] = zv;
      }
    }
    __syncthreads();

    // ---- gate phase (unit u = t, threads 0..255) -------------------------
    if (t < 256) {
      const float4 zv = *reinterpret_cast<const float4*>(&zbuf4[t << 2]);
      const float z0 = zx.x + zv.x;
      const float z1 = zx.y + zv.y;
      const float z2 = zx.z + zv.z;
      const float z3 = zx.w + zv.w;
      const float ig = fsigmoid(z0);
      const float fg = fsigmoid(z1);
      const float gg = ftanh(z2);
      const float og = fsigmoid(z3);
      c_reg = fg * c_reg + ig * gg;
      const float hval = og * ftanh(c_reg);
      const int trow = dir ? (LL - 1 - s) : s;
      Hall[(size_t)trow * HH + t] = hval;
      const float hnb = dpp_f<0xB1>(hval);   // neighbor t^1 in quad
      if ((t & 1) == 0)
        h16u[(npar << 7) + (t >> 1)] = pack_u(hval, hnb);
    }
    __syncthreads();
    zx = nzx;
  }
}

// ---------------------------------------------------------------------------
// Kernel 4: feats
// ---------------------------------------------------------------------------
__global__ __launch_bounds__(256) void feats_gemm(
    const float* __restrict__ HALL, const float* __restrict__ Wout,
    const float* __restrict__ bout, float* __restrict__ FE) {
  __shared__ float Wl[16][516];
  const int t = threadIdx.x;
  for (int i = t; i < 16 * 512; i += 256) Wl[i >> 9][i & 511] = Wout[i];
  __syncthreads();
  const int row = blockIdx.x * 16 + (t >> 4);
  const int j = t & 15;
  const float* hf = HALL + (size_t)row * HH;
  const float* hb = HALL + (size_t)LL * HH + (size_t)row * HH;
  float acc = bout[j];
  for (int k = 0; k < HH; k += 4) {
    const float4 a = *reinterpret_cast<const float4*>(hf + k);
    const float4 wa = *reinterpret_cast<const float4*>(&Wl[j][k]);
    acc += a.x * wa.x + a.y * wa.y + a.z * wa.z + a.w * wa.w;
    const float4 b2 = *reinterpret_cast<const float4*>(hb + k);
    const float4 wb = *reinterpret_cast<const float4*>(&Wl[j][256 + k]);
    acc += b2.x * wb.x + b2.y * wb.y + b2.z * wb.z + b2.w * wb.w;
  }
  FE[(size_t)row * TT + j] = acc;
}

// ---------------------------------------------------------------------------
// Kernel 5: Viterbi (unchanged)
// ---------------------------------------------------------------------------
__global__ __launch_bounds__(1024) void viterbi(
    const float* __restrict__ FE, const float* __restrict__ trans,
    float* __restrict__ out) {
  __shared__ unsigned char bp8[LL * TT];
  __shared__ unsigned char xc[64 * 16];
  __shared__ unsigned char entry[64];
  __shared__ int sbest;
  const int t = threadIdx.x;

  if (t < 64) {
    const int n = t >> 2, pg = t & 3;
    const float tr0 = trans[n * 16 + (pg << 2) + 0];
    const float tr1 = trans[n * 16 + (pg << 2) + 1];
    const float tr2 = trans[n * 16 + (pg << 2) + 2];
    const float tr3 = trans[n * 16 + (pg << 2) + 3];
    float fvp0 = ((pg << 2) + 0 == 14) ? 0.f : NEGV;
    float fvp1 = ((pg << 2) + 1 == 14) ? 0.f : NEGV;
    float fvp2 = ((pg << 2) + 2 == 14) ? 0.f : NEGV;
    float fvp3 = ((pg << 2) + 3 == 14) ? 0.f : NEGV;

    auto step = [&](int s, float feat) {
      float bv = fvp0 + tr0; int bi = (pg << 2);
      float c;
      c = fvp1 + tr1; if (c > bv) { bv = c; bi = (pg << 2) + 1; }
      c = fvp2 + tr2; if (c > bv) { bv = c; bi = (pg << 2) + 2; }
      c = fvp3 + tr3; if (c > bv) { bv = c; bi = (pg << 2) + 3; }
      float pv = dpp_f<0xB1>(bv); int pi = dpp_i<0xB1>(bi);
      if (pv > bv || (pv == bv && pi < bi)) { bv = pv; bi = pi; }
      pv = dpp_f<0x4E>(bv); pi = dpp_i<0x4E>(bi);
      if (pv > bv || (pv == bv && pi < bi)) { bv = pv; bi = pi; }
      if (pg == 0) bp8[(s << 4) + n] = (unsigned char)bi;
      const float fvn = bv + feat;
      fvp0 = bperm_f((pg << 4) + 0,  fvn);
      fvp1 = bperm_f((pg << 4) + 4,  fvn);
      fvp2 = bperm_f((pg << 4) + 8,  fvn);
      fvp3 = bperm_f((pg << 4) + 12, fvn);
    };

    float fb0 = FE[(0 << 4) + n], fb1 = FE[(1 << 4) + n];
    float fb2 = FE[(2 << 4) + n], fb3 = FE[(3 << 4) + n];
    for (int s = 0; s < LL; s += 4) {
      step(s + 0, fb0); fb0 = (s + 4 < LL) ? FE[((s + 4) << 4) + n] : 0.f;
      step(s + 1, fb1); fb1 = (s + 5 < LL) ? FE[((s + 5) << 4) + n] : 0.f;
      step(s + 2, fb2); fb2 = (s + 6 < LL) ? FE[((s + 6) << 4) + n] : 0.f;
      step(s + 3, fb3); fb3 = (s + 7 < LL) ? FE[((s + 7) << 4) + n] : 0.f;
    }

    const float tt0 = trans[240 + (pg << 2) + 0];
    const float tt1 = trans[240 + (pg << 2) + 1];
    const float tt2 = trans[240 + (pg << 2) + 2];
    const float tt3 = trans[240 + (pg << 2) + 3];
    float bv = fvp0 + tt0; int bi = (pg << 2);
    float c;
    c = fvp1 + tt1; if (c > bv) { bv = c; bi = (pg << 2) + 1; }
    c = fvp2 + tt2; if (c > bv) { bv = c; bi = (pg << 2) + 2; }
    c = fvp3 + tt3; if (c > bv) { bv = c; bi = (pg << 2) + 3; }
    float pv = dpp_f<0xB1>(bv); int pi = dpp_i<0xB1>(bi);
    if (pv > bv || (pv == bv && pi < bi)) { bv = pv; bi = pi; }
    pv = dpp_f<0x4E>(bv); pi = dpp_i<0x4E>(bi);
    if (pv > bv || (pv == bv && pi < bi)) { bv = pv; bi = pi; }
    if (t == 0) { out[0] = bv; sbest = bi; }
  }
  __syncthreads();

  {
    const int c = t >> 4, e = t & 15;
    int tag = e;
#pragma unroll 1
    for (int i = 63; i >= 0; --i) tag = bp8[(((c << 6) + i) << 4) + tag];
    xc[(c << 4) + e] = (unsigned char)tag;
  }
  __syncthreads();
  if (t == 0) {
    int carry = sbest;
#pragma unroll 1
    for (int c = 63; c >= 0; --c) {
      entry[c] = (unsigned char)carry;
      carry = xc[(c << 4) + carry];
    }
  }
  __syncthreads();
  if (t < 64) {
    const int c = t;
    int tag = entry[c];
#pragma unroll 1
    for (int i = 63; i >= 0; --i) {
      const int s = (c << 6) + i;
      out[1 + s] = (float)tag;
      tag = bp8[(s << 4) + tag];
    }
  }
}

// ---------------------------------------------------------------------------
extern "C" void kernel_launch(void* const* d_in, const int* in_sizes, int n_in,
                              void* d_out, int out_size, void* d_ws, size_t ws_size,
                              hipStream_t stream) {
  const int*   sent = (const int*)d_in[0];
  const float* emb  = (const float*)d_in[1];
  const float* wihf = (const float*)d_in[2];
  const float* whhf = (const float*)d_in[3];
  const float* bf   = (const float*)d_in[4];
  const float* wihb = (const float*)d_in[5];
  const float* whhb = (const float*)d_in[6];
  const float* bb   = (const float*)d_in[7];
  const float* wout = (const float*)d_in[8];
  const float* bout = (const float*)d_in[9];
  const float* trans= (const float*)d_in[10];
  const float* h0   = (const float*)d_in[11];
  const float* c0   = (const float*)d_in[12];
  float* out = (float*)d_out;
  char* ws = (char*)d_ws;

  float* X    = (float*)(ws + OFF_X);
  float* ZX   = (float*)(ws + OFF_ZX);
  float* HALL = (float*)(ws + OFF_HALL);
  float* FE   = (float*)(ws + OFF_FE);

  gather_x<<<(LL * (EE / 4) + 255) / 256, 256, 0, stream>>>(sent, emb, X);
  input_gemm<<<dim3(16, 64, 2), 256, 0, stream>>>(X, wihf, bf, wihb, bb, ZX);
  recurrence<<<2, 512, 0, stream>>>(whhf, whhb, h0, c0, ZX, HALL);
  feats_gemm<<<LL / 16, 256, 0, stream>>>(HALL, wout, bout, FE);
  viterbi<<<1, 1024, 0, stream>>>(FE, trans, out);
}

// Round 8
// 7101.245 us; speedup vs baseline: 1.5013x; 1.5013x over previous
//
#include <hip/hip_runtime.h>
#include <math.h>
#include <stdint.h>

// Problem constants
constexpr int LL = 4096;   // seq len
constexpr int EE = 300;    // embedding dim
constexpr int HH = 256;    // per-direction hidden (H2)
constexpr int NGATE = 1024;// 4*HH
constexpr int TT = 16;     // tagset
constexpr float NEGV = -10000.0f;

typedef _Float16 v2h __attribute__((ext_vector_type(2)));
typedef _Float16 v8h __attribute__((ext_vector_type(8)));
typedef float v4f __attribute__((ext_vector_type(4)));

// Workspace layout (byte offsets)
constexpr size_t OFF_X    = 16384;
constexpr size_t OFF_ZX   = OFF_X    + (size_t)LL*EE*4;     // 2*L*1024 f32
constexpr size_t OFF_HALL = OFF_ZX   + (size_t)2*LL*NGATE*4;// 2*L*256 f32
constexpr size_t OFF_FE   = OFF_HALL + (size_t)2*LL*HH*4;   // L*16 f32

__device__ __forceinline__ v2h pack_h2(float x, float y) {
  return __builtin_bit_cast(v2h, __builtin_amdgcn_cvt_pkrtz(x, y));
}
__device__ __forceinline__ unsigned pack_u(float x, float y) {
  return __builtin_bit_cast(unsigned, __builtin_amdgcn_cvt_pkrtz(x, y));
}
__device__ __forceinline__ v8h make_v8h(v2h a, v2h b, v2h c, v2h d) {
  union { v2h p[4]; v8h v; } u; u.p[0]=a; u.p[1]=b; u.p[2]=c; u.p[3]=d; return u.v;
}

__device__ __forceinline__ float fsigmoid(float x) {
  return __builtin_amdgcn_rcpf(1.f + __expf(-x));
}
__device__ __forceinline__ float ftanh(float x) {
  return 1.f - 2.f * __builtin_amdgcn_rcpf(1.f + __expf(2.f * x));
}

template <int CTRL>
__device__ __forceinline__ int dpp_i(int v) {
  return __builtin_amdgcn_mov_dpp(v, CTRL, 0xF, 0xF, true);
}
template <int CTRL>
__device__ __forceinline__ float dpp_f(float v) {
  return __int_as_float(__builtin_amdgcn_mov_dpp(__float_as_int(v), CTRL, 0xF, 0xF, true));
}
__device__ __forceinline__ float bperm_f(int lane, float v) {
  return __int_as_float(__builtin_amdgcn_ds_bpermute(lane << 2, __float_as_int(v)));
}

// ---------------------------------------------------------------------------
// Kernel 1: embedding gather
// ---------------------------------------------------------------------------
__global__ void gather_x(const int* __restrict__ sent, const float* __restrict__ emb,
                         float* __restrict__ X) {
  const int i = blockIdx.x * blockDim.x + threadIdx.x;
  const int total = LL * (EE / 4);
  if (i >= total) return;
  const int row = i / (EE / 4), c4 = i % (EE / 4);
  const int v = sent[row];
  reinterpret_cast<float4*>(X)[(size_t)row * (EE / 4) + c4] =
      reinterpret_cast<const float4*>(emb + (size_t)v * EE)[c4];
}

// ---------------------------------------------------------------------------
// Kernel 2: input GEMM, GATE-TRANSPOSED store: Zx[t][unit*4+gate]
// (unchanged — validated R5/R6/R7)
// ---------------------------------------------------------------------------
__global__ __launch_bounds__(256) void input_gemm(
    const float* __restrict__ X, const float* __restrict__ w_f,
    const float* __restrict__ b_f, const float* __restrict__ w_b,
    const float* __restrict__ b_b, float* __restrict__ ZX) {
  const int dir = blockIdx.z;
  const float* __restrict__ W  = dir ? w_b : w_f;
  const float* __restrict__ Bv = dir ? b_b : b_f;
  float* __restrict__ Z = ZX + (size_t)dir * LL * NGATE;
  __shared__ float As[32][68];
  __shared__ float Bs[32][68];
  const int m0 = blockIdx.y * 64, n0 = blockIdx.x * 64;
  const int t = threadIdx.x;
  const int tx = t & 15, ty = t >> 4;
  float acc[4][4] = {};
  for (int k0 = 0; k0 < EE; k0 += 32) {
#pragma unroll
    for (int r = 0; r < 2; ++r) {
      const int idx = t + r * 256;
      const int row = idx >> 3;
      const int kk4 = (idx & 7) << 2;
      const int k = k0 + kk4;
      float4 va = make_float4(0.f, 0.f, 0.f, 0.f), vb = va;
      if (k < EE) {
        va = *reinterpret_cast<const float4*>(X + (size_t)(m0 + row) * EE + k);
        vb = *reinterpret_cast<const float4*>(W + (size_t)(n0 + row) * EE + k);
      }
      As[kk4 + 0][row] = va.x; As[kk4 + 1][row] = va.y;
      As[kk4 + 2][row] = va.z; As[kk4 + 3][row] = va.w;
      Bs[kk4 + 0][row] = vb.x; Bs[kk4 + 1][row] = vb.y;
      Bs[kk4 + 2][row] = vb.z; Bs[kk4 + 3][row] = vb.w;
    }
    __syncthreads();
    const int kmax = (EE - k0 < 32) ? (EE - k0) : 32;
    for (int k = 0; k < kmax; ++k) {
      const float4 av = *reinterpret_cast<const float4*>(&As[k][ty << 2]);
      const float4 bv = *reinterpret_cast<const float4*>(&Bs[k][tx << 2]);
      acc[0][0] += av.x * bv.x; acc[0][1] += av.x * bv.y; acc[0][2] += av.x * bv.z; acc[0][3] += av.x * bv.w;
      acc[1][0] += av.y * bv.x; acc[1][1] += av.y * bv.y; acc[1][2] += av.y * bv.z; acc[1][3] += av.y * bv.w;
      acc[2][0] += av.z * bv.x; acc[2][1] += av.z * bv.y; acc[2][2] += av.z * bv.z; acc[2][3] += av.z * bv.w;
      acc[3][0] += av.w * bv.x; acc[3][1] += av.w * bv.y; acc[3][2] += av.w * bv.z; acc[3][3] += av.w * bv.w;
    }
    __syncthreads();
  }
#pragma unroll
  for (int i = 0; i < 4; ++i)
#pragma unroll
    for (int j = 0; j < 4; ++j) {
      const int m = m0 + (ty << 2) + i, n = n0 + (tx << 2) + j;
      Z[(size_t)m * NGATE + (((n & 255) << 2) | (n >> 8))] = acc[i][j] + Bv[n];
    }
}

// ---------------------------------------------------------------------------
// Kernel 3: persistent bidirectional LSTM recurrence — R2's proven all-MFMA
// single-WG-per-direction structure, with two surgical fixes:
//
//  FIX 1 (the mechanism target): R2's 19 LDS-streamed B-frags were frag ids
//  45..63 = concentrated in kc 6,7 — the loop TAIL issued 16 ds_read_b128
//  (~120 cy each) with no reg-resident MFMAs left to hide them. Now the same
//  19 LDS frags are distributed EVENLY: tn in {6,7} for all kc (16) plus
//  tn=5 for kc>=5 (3) -> every kc iteration has 5-6 reg MFMAs (~110 cy) to
//  cover its 2-3 LDS reads.  Reg frags: bregA[8][5] + bregB[5] = 180 regs
//  (exactly R2's clean count; ~252 unified total, VGPR_Count 128).
//
//  FIX 2: gate-transposed zbuf4 + ZX (validated R5-R7): gate phase is ONE
//  float4 LDS read + ONE float4 global prefetch instead of 4+4 scalars.
//
// Layout (R2-verified): wave w owns n in [w*128,(w+1)*128), 8 tiles of 16.
// B-frag (kc,tn): lane l holds W[(w<<7)+(tn<<4)+(l&15)][kc*32+(l>>4)*8+j].
// A-frag: h replicated across rows (lane l reads h[kc*32+(l>>4)*8..+8]);
// A/B share the (quadrant,slot)->k map so HW k-permutation cancels; C/D
// read col=lane&15 only, acc[tn][0] valid on ALL lanes (replicated A).
// MFMA pipe floor: 512 chunks x 4.85 cy = 2483 cy/step; target ~3100.
// ---------------------------------------------------------------------------
__global__ __launch_bounds__(512) __attribute__((amdgpu_waves_per_eu(2, 2)))
void recurrence(
    const float* __restrict__ whh_f, const float* __restrict__ whh_b,
    const float* __restrict__ h0, const float* __restrict__ c0,
    const float* __restrict__ ZX, float* __restrict__ HALL) {
  const int dir = blockIdx.x;
  const int t = threadIdx.x;
  const int w = t >> 6;            // wave 0..7
  const int l = t & 63;
  const int lcol = l & 15;
  const int lq = l >> 4;           // quadrant 0..3
  const float* __restrict__ Whh = dir ? whh_b : whh_f;
  const float* __restrict__ Z = ZX + (size_t)dir * LL * NGATE;
  float* __restrict__ Hall = HALL + (size_t)dir * LL * HH;

  __shared__ uint4 WL[8 * 19 * 64];                 // 152 KB LDS B-frags
  __shared__ __align__(16) float zbuf4[NGATE];      // 4 KB, [unit][gate]
  __shared__ __align__(16) unsigned h16u[2 * 128];  // packed f16 h, parity dbuf

  // ---- preamble: build B-frags from W_hh (f32 -> f16 RTZ) ----------------
  // LDS ids: tn=6 -> 2kc; tn=7 -> 2kc+1; tn=5,kc>=5 -> 16+(kc-5)
  v8h bregA[8][5];
  v8h bregB[5];
#pragma unroll
  for (int kc = 0; kc < 8; ++kc) {
#pragma unroll
    for (int tn = 0; tn < 8; ++tn) {
      const int n = (w << 7) + (tn << 4) + lcol;
      const float* wp = Whh + (size_t)n * HH + (kc << 5) + (lq << 3);
      const float4 a4 = *reinterpret_cast<const float4*>(wp);
      const float4 b4 = *reinterpret_cast<const float4*>(wp + 4);
      const v8h f = make_v8h(pack_h2(a4.x, a4.y), pack_h2(a4.z, a4.w),
                             pack_h2(b4.x, b4.y), pack_h2(b4.z, b4.w));
      if (tn < 5) {
        bregA[kc][tn] = f;
      } else if (tn == 5) {
        if (kc < 5) bregB[kc] = f;
        else WL[(w * 19 + 16 + (kc - 5)) * 64 + l] = __builtin_bit_cast(uint4, f);
      } else {
        WL[(w * 19 + 2 * kc + (tn - 6)) * 64 + l] = __builtin_bit_cast(uint4, f);
      }
    }
  }

  // ---- state init --------------------------------------------------------
  float c_reg = 0.f;
  if (t < 256) c_reg = c0[dir * HH + t];
  if (t < 128)
    h16u[t] = pack_u(h0[dir * HH + 2 * t], h0[dir * HH + 2 * t + 1]);

  float4 zx = make_float4(0.f, 0.f, 0.f, 0.f);
  if (t < 256) {
    const int trow0 = dir ? (LL - 1) : 0;
    zx = *reinterpret_cast<const float4*>(Z + (size_t)trow0 * NGATE + 4 * t);
  }
  __syncthreads();

  const char* h16b = reinterpret_cast<const char*>(h16u);

  for (int s = 0; s < LL; ++s) {
    const int par = s & 1;
    // prefetch next step's Zx (one float4; hides under the matvec)
    float4 nzx = make_float4(0.f, 0.f, 0.f, 0.f);
    if (t < 256 && s + 1 < LL) {
      const int trow = dir ? (LL - 2 - s) : (s + 1);
      nzx = *reinterpret_cast<const float4*>(Z + (size_t)trow * NGATE + 4 * t);
    }

    const uint4* hq = reinterpret_cast<const uint4*>(h16b + (par << 9));

    // ---- MFMA phase: z[n] = sum_k W[n][k] h[k] ---------------------------
    v4f acc0 = {0.f,0.f,0.f,0.f}, acc1 = {0.f,0.f,0.f,0.f};
    v4f acc2 = {0.f,0.f,0.f,0.f}, acc3 = {0.f,0.f,0.f,0.f};
    v4f acc4 = {0.f,0.f,0.f,0.f}, acc5 = {0.f,0.f,0.f,0.f};
    v4f acc6 = {0.f,0.f,0.f,0.f}, acc7 = {0.f,0.f,0.f,0.f};
#pragma unroll
    for (int kc = 0; kc < 8; ++kc) {
      // LDS reads for THIS iteration issue first; the 5-6 reg MFMAs below
      // cover their latency.
      const uint4 u6 = WL[(w * 19 + 2 * kc + 0) * 64 + l];
      const uint4 u7 = WL[(w * 19 + 2 * kc + 1) * 64 + l];
      uint4 u5;
      if (kc >= 5) u5 = WL[(w * 19 + 16 + (kc - 5)) * 64 + l];
      const v8h ah = __builtin_bit_cast(v8h, hq[(kc << 2) + lq]);
      acc0 = __builtin_amdgcn_mfma_f32_16x16x32_f16(ah, bregA[kc][0], acc0, 0, 0, 0);
      acc1 = __builtin_amdgcn_mfma_f32_16x16x32_f16(ah, bregA[kc][1], acc1, 0, 0, 0);
      acc2 = __builtin_amdgcn_mfma_f32_16x16x32_f16(ah, bregA[kc][2], acc2, 0, 0, 0);
      acc3 = __builtin_amdgcn_mfma_f32_16x16x32_f16(ah, bregA[kc][3], acc3, 0, 0, 0);
      acc4 = __builtin_amdgcn_mfma_f32_16x16x32_f16(ah, bregA[kc][4], acc4, 0, 0, 0);
      if (kc < 5)
        acc5 = __builtin_amdgcn_mfma_f32_16x16x32_f16(ah, bregB[kc], acc5, 0, 0, 0);
      else
        acc5 = __builtin_amdgcn_mfma_f32_16x16x32_f16(ah, __builtin_bit_cast(v8h, u5), acc5, 0, 0, 0);
      acc6 = __builtin_amdgcn_mfma_f32_16x16x32_f16(ah, __builtin_bit_cast(v8h, u6), acc6, 0, 0, 0);
      acc7 = __builtin_amdgcn_mfma_f32_16x16x32_f16(ah, __builtin_bit_cast(v8h, u7), acc7, 0, 0, 0);
    }

    // ---- z writes: lane (lq,lcol) writes tiles lq and lq+4 ---------------
    {
      const int n1 = (w << 7) + (lq << 4) + lcol;
      const int n2 = n1 + 64;
      const float z1 = (lq == 0) ? acc0[0] : (lq == 1) ? acc1[0]
                      : (lq == 2) ? acc2[0] : acc3[0];
      const float z2 = (lq == 0) ? acc4[0] : (lq == 1) ? acc5[0]
                      : (lq == 2) ? acc6[0] : acc7[0];
      zbuf4[((n1 & 255) << 2) | (n1 >> 8)] = z1;
      zbuf4[((n2 & 255) << 2) | (n2 >> 8)] = z2;
    }
    __syncthreads();

    // ---- gate phase (unit u = t, threads 0..255) -------------------------
    if (t < 256) {
      const float4 zv = *reinterpret_cast<const float4*>(&zbuf4[t << 2]);
      const float z0 = zx.x + zv.x;
      const float z1 = zx.y + zv.y;
      const float z2 = zx.z + zv.z;
      const float z3 = zx.w + zv.w;
      const float ig = fsigmoid(z0);
      const float fg = fsigmoid(z1);
      const float gg = ftanh(z2);
      const float og = fsigmoid(z3);
      c_reg = fg * c_reg + ig * gg;
      const float hval = og * ftanh(c_reg);
      const int trow = dir ? (LL - 1 - s) : s;
      Hall[(size_t)trow * HH + t] = hval;
      const float hnb = dpp_f<0xB1>(hval);   // neighbor (t^1) within quad
      if ((t & 1) == 0)
        h16u[((par ^ 1) << 7) + (t >> 1)] = pack_u(hval, hnb);
    }
    __syncthreads();
    zx = nzx;
  }
}

// ---------------------------------------------------------------------------
// Kernel 4: feats
// ---------------------------------------------------------------------------
__global__ __launch_bounds__(256) void feats_gemm(
    const float* __restrict__ HALL, const float* __restrict__ Wout,
    const float* __restrict__ bout, float* __restrict__ FE) {
  __shared__ float Wl[16][516];
  const int t = threadIdx.x;
  for (int i = t; i < 16 * 512; i += 256) Wl[i >> 9][i & 511] = Wout[i];
  __syncthreads();
  const int row = blockIdx.x * 16 + (t >> 4);
  const int j = t & 15;
  const float* hf = HALL + (size_t)row * HH;
  const float* hb = HALL + (size_t)LL * HH + (size_t)row * HH;
  float acc = bout[j];
  for (int k = 0; k < HH; k += 4) {
    const float4 a = *reinterpret_cast<const float4*>(hf + k);
    const float4 wa = *reinterpret_cast<const float4*>(&Wl[j][k]);
    acc += a.x * wa.x + a.y * wa.y + a.z * wa.z + a.w * wa.w;
    const float4 b2 = *reinterpret_cast<const float4*>(hb + k);
    const float4 wb = *reinterpret_cast<const float4*>(&Wl[j][256 + k]);
    acc += b2.x * wb.x + b2.y * wb.y + b2.z * wb.z + b2.w * wb.w;
  }
  FE[(size_t)row * TT + j] = acc;
}

// ---------------------------------------------------------------------------
// Kernel 5: Viterbi (unchanged)
// ---------------------------------------------------------------------------
__global__ __launch_bounds__(1024) void viterbi(
    const float* __restrict__ FE, const float* __restrict__ trans,
    float* __restrict__ out) {
  __shared__ unsigned char bp8[LL * TT];
  __shared__ unsigned char xc[64 * 16];
  __shared__ unsigned char entry[64];
  __shared__ int sbest;
  const int t = threadIdx.x;

  if (t < 64) {
    const int n = t >> 2, pg = t & 3;
    const float tr0 = trans[n * 16 + (pg << 2) + 0];
    const float tr1 = trans[n * 16 + (pg << 2) + 1];
    const float tr2 = trans[n * 16 + (pg << 2) + 2];
    const float tr3 = trans[n * 16 + (pg << 2) + 3];
    float fvp0 = ((pg << 2) + 0 == 14) ? 0.f : NEGV;
    float fvp1 = ((pg << 2) + 1 == 14) ? 0.f : NEGV;
    float fvp2 = ((pg << 2) + 2 == 14) ? 0.f : NEGV;
    float fvp3 = ((pg << 2) + 3 == 14) ? 0.f : NEGV;

    auto step = [&](int s, float feat) {
      float bv = fvp0 + tr0; int bi = (pg << 2);
      float c;
      c = fvp1 + tr1; if (c > bv) { bv = c; bi = (pg << 2) + 1; }
      c = fvp2 + tr2; if (c > bv) { bv = c; bi = (pg << 2) + 2; }
      c = fvp3 + tr3; if (c > bv) { bv = c; bi = (pg << 2) + 3; }
      float pv = dpp_f<0xB1>(bv); int pi = dpp_i<0xB1>(bi);
      if (pv > bv || (pv == bv && pi < bi)) { bv = pv; bi = pi; }
      pv = dpp_f<0x4E>(bv); pi = dpp_i<0x4E>(bi);
      if (pv > bv || (pv == bv && pi < bi)) { bv = pv; bi = pi; }
      if (pg == 0) bp8[(s << 4) + n] = (unsigned char)bi;
      const float fvn = bv + feat;
      fvp0 = bperm_f((pg << 4) + 0,  fvn);
      fvp1 = bperm_f((pg << 4) + 4,  fvn);
      fvp2 = bperm_f((pg << 4) + 8,  fvn);
      fvp3 = bperm_f((pg << 4) + 12, fvn);
    };

    float fb0 = FE[(0 << 4) + n], fb1 = FE[(1 << 4) + n];
    float fb2 = FE[(2 << 4) + n], fb3 = FE[(3 << 4) + n];
    for (int s = 0; s < LL; s += 4) {
      step(s + 0, fb0); fb0 = (s + 4 < LL) ? FE[((s + 4) << 4) + n] : 0.f;
      step(s + 1, fb1); fb1 = (s + 5 < LL) ? FE[((s + 5) << 4) + n] : 0.f;
      step(s + 2, fb2); fb2 = (s + 6 < LL) ? FE[((s + 6) << 4) + n] : 0.f;
      step(s + 3, fb3); fb3 = (s + 7 < LL) ? FE[((s + 7) << 4) + n] : 0.f;
    }

    const float tt0 = trans[240 + (pg << 2) + 0];
    const float tt1 = trans[240 + (pg << 2) + 1];
    const float tt2 = trans[240 + (pg << 2) + 2];
    const float tt3 = trans[240 + (pg << 2) + 3];
    float bv = fvp0 + tt0; int bi = (pg << 2);
    float c;
    c = fvp1 + tt1; if (c > bv) { bv = c; bi = (pg << 2) + 1; }
    c = fvp2 + tt2; if (c > bv) { bv = c; bi = (pg << 2) + 2; }
    c = fvp3 + tt3; if (c > bv) { bv = c; bi = (pg << 2) + 3; }
    float pv = dpp_f<0xB1>(bv); int pi = dpp_i<0xB1>(bi);
    if (pv > bv || (pv == bv && pi < bi)) { bv = pv; bi = pi; }
    pv = dpp_f<0x4E>(bv); pi = dpp_i<0x4E>(bi);
    if (pv > bv || (pv == bv && pi < bi)) { bv = pv; bi = pi; }
    if (t == 0) { out[0] = bv; sbest = bi; }
  }
  __syncthreads();

  {
    const int c = t >> 4, e = t & 15;
    int tag = e;
#pragma unroll 1
    for (int i = 63; i >= 0; --i) tag = bp8[(((c << 6) + i) << 4) + tag];
    xc[(c << 4) + e] = (unsigned char)tag;
  }
  __syncthreads();
  if (t == 0) {
    int carry = sbest;
#pragma unroll 1
    for (int c = 63; c >= 0; --c) {
      entry[c] = (unsigned char)carry;
      carry = xc[(c << 4) + carry];
    }
  }
  __syncthreads();
  if (t < 64) {
    const int c = t;
    int tag = entry[c];
#pragma unroll 1
    for (int i = 63; i >= 0; --i) {
      const int s = (c << 6) + i;
      out[1 + s] = (float)tag;
      tag = bp8[(s << 4) + tag];
    }
  }
}

// ---------------------------------------------------------------------------
extern "C" void kernel_launch(void* const* d_in, const int* in_sizes, int n_in,
                              void* d_out, int out_size, void* d_ws, size_t ws_size,
                              hipStream_t stream) {
  const int*   sent = (const int*)d_in[0];
  const float* emb  = (const float*)d_in[1];
  const float* wihf = (const float*)d_in[2];
  const float* whhf = (const float*)d_in[3];
  const float* bf   = (const float*)d_in[4];
  const float* wihb = (const float*)d_in[5];
  const float* whhb = (const float*)d_in[6];
  const float* bb   = (const float*)d_in[7];
  const float* wout = (const float*)d_in[8];
  const float* bout = (const float*)d_in[9];
  const float* trans= (const float*)d_in[10];
  const float* h0   = (const float*)d_in[11];
  const float* c0   = (const float*)d_in[12];
  float* out = (float*)d_out;
  char* ws = (char*)d_ws;

  float* X    = (float*)(ws + OFF_X);
  float* ZX   = (float*)(ws + OFF_ZX);
  float* HALL = (float*)(ws + OFF_HALL);
  float* FE   = (float*)(ws + OFF_FE);

  gather_x<<<(LL * (EE / 4) + 255) / 256, 256, 0, stream>>>(sent, emb, X);
  input_gemm<<<dim3(16, 64, 2), 256, 0, stream>>>(X, wihf, bf, wihb, bb, ZX);
  recurrence<<<2, 512, 0, stream>>>(whhf, whhb, h0, c0, ZX, HALL);
  feats_gemm<<<LL / 16, 256, 0, stream>>>(HALL, wout, bout, FE);
  viterbi<<<1, 1024, 0, stream>>>(FE, trans, out);
}

// Round 9
// 6473.252 us; speedup vs baseline: 1.6470x; 1.0970x over previous
//
#include <hip/hip_runtime.h>
#include <math.h>
#include <stdint.h>

// Problem constants
constexpr int LL = 4096;   // seq len
constexpr int EE = 300;    // embedding dim
constexpr int HH = 256;    // per-direction hidden (H2)
constexpr int NGATE = 1024;// 4*HH
constexpr int TT = 16;     // tagset
constexpr float NEGV = -10000.0f;

typedef _Float16 v2h __attribute__((ext_vector_type(2)));
typedef _Float16 v8h __attribute__((ext_vector_type(8)));
typedef float v4f __attribute__((ext_vector_type(4)));

// Workspace layout (byte offsets)
constexpr size_t OFF_X    = 16384;
constexpr size_t OFF_ZX   = OFF_X    + (size_t)LL*EE*4;     // 2*L*1024 f32
constexpr size_t OFF_HALL = OFF_ZX   + (size_t)2*LL*NGATE*4;// 2*L*256 f32
constexpr size_t OFF_FE   = OFF_HALL + (size_t)2*LL*HH*4;   // L*16 f32

__device__ __forceinline__ v2h pack_h2(float x, float y) {
  return __builtin_bit_cast(v2h, __builtin_amdgcn_cvt_pkrtz(x, y));
}
__device__ __forceinline__ unsigned pack_u(float x, float y) {
  return __builtin_bit_cast(unsigned, __builtin_amdgcn_cvt_pkrtz(x, y));
}
__device__ __forceinline__ v8h make_v8h(v2h a, v2h b, v2h c, v2h d) {
  union { v2h p[4]; v8h v; } u; u.p[0]=a; u.p[1]=b; u.p[2]=c; u.p[3]=d; return u.v;
}

__device__ __forceinline__ float fsigmoid(float x) {
  return __builtin_amdgcn_rcpf(1.f + __expf(-x));
}
__device__ __forceinline__ float ftanh(float x) {
  return 1.f - 2.f * __builtin_amdgcn_rcpf(1.f + __expf(2.f * x));
}

template <int CTRL>
__device__ __forceinline__ int dpp_i(int v) {
  return __builtin_amdgcn_mov_dpp(v, CTRL, 0xF, 0xF, true);
}
template <int CTRL>
__device__ __forceinline__ float dpp_f(float v) {
  return __int_as_float(__builtin_amdgcn_mov_dpp(__float_as_int(v), CTRL, 0xF, 0xF, true));
}
__device__ __forceinline__ float bperm_f(int lane, float v) {
  return __int_as_float(__builtin_amdgcn_ds_bpermute(lane << 2, __float_as_int(v)));
}

// ---------------------------------------------------------------------------
// Kernel 1: embedding gather
// ---------------------------------------------------------------------------
__global__ void gather_x(const int* __restrict__ sent, const float* __restrict__ emb,
                         float* __restrict__ X) {
  const int i = blockIdx.x * blockDim.x + threadIdx.x;
  const int total = LL * (EE / 4);
  if (i >= total) return;
  const int row = i / (EE / 4), c4 = i % (EE / 4);
  const int v = sent[row];
  reinterpret_cast<float4*>(X)[(size_t)row * (EE / 4) + c4] =
      reinterpret_cast<const float4*>(emb + (size_t)v * EE)[c4];
}

// ---------------------------------------------------------------------------
// Kernel 2: input GEMM, GATE-TRANSPOSED store: Zx[t][unit*4+gate]
// (unchanged — validated R5-R8)
// ---------------------------------------------------------------------------
__global__ __launch_bounds__(256) void input_gemm(
    const float* __restrict__ X, const float* __restrict__ w_f,
    const float* __restrict__ b_f, const float* __restrict__ w_b,
    const float* __restrict__ b_b, float* __restrict__ ZX) {
  const int dir = blockIdx.z;
  const float* __restrict__ W  = dir ? w_b : w_f;
  const float* __restrict__ Bv = dir ? b_b : b_f;
  float* __restrict__ Z = ZX + (size_t)dir * LL * NGATE;
  __shared__ float As[32][68];
  __shared__ float Bs[32][68];
  const int m0 = blockIdx.y * 64, n0 = blockIdx.x * 64;
  const int t = threadIdx.x;
  const int tx = t & 15, ty = t >> 4;
  float acc[4][4] = {};
  for (int k0 = 0; k0 < EE; k0 += 32) {
#pragma unroll
    for (int r = 0; r < 2; ++r) {
      const int idx = t + r * 256;
      const int row = idx >> 3;
      const int kk4 = (idx & 7) << 2;
      const int k = k0 + kk4;
      float4 va = make_float4(0.f, 0.f, 0.f, 0.f), vb = va;
      if (k < EE) {
        va = *reinterpret_cast<const float4*>(X + (size_t)(m0 + row) * EE + k);
        vb = *reinterpret_cast<const float4*>(W + (size_t)(n0 + row) * EE + k);
      }
      As[kk4 + 0][row] = va.x; As[kk4 + 1][row] = va.y;
      As[kk4 + 2][row] = va.z; As[kk4 + 3][row] = va.w;
      Bs[kk4 + 0][row] = vb.x; Bs[kk4 + 1][row] = vb.y;
      Bs[kk4 + 2][row] = vb.z; Bs[kk4 + 3][row] = vb.w;
    }
    __syncthreads();
    const int kmax = (EE - k0 < 32) ? (EE - k0) : 32;
    for (int k = 0; k < kmax; ++k) {
      const float4 av = *reinterpret_cast<const float4*>(&As[k][ty << 2]);
      const float4 bv = *reinterpret_cast<const float4*>(&Bs[k][tx << 2]);
      acc[0][0] += av.x * bv.x; acc[0][1] += av.x * bv.y; acc[0][2] += av.x * bv.z; acc[0][3] += av.x * bv.w;
      acc[1][0] += av.y * bv.x; acc[1][1] += av.y * bv.y; acc[1][2] += av.y * bv.z; acc[1][3] += av.y * bv.w;
      acc[2][0] += av.z * bv.x; acc[2][1] += av.z * bv.y; acc[2][2] += av.z * bv.z; acc[2][3] += av.z * bv.w;
      acc[3][0] += av.w * bv.x; acc[3][1] += av.w * bv.y; acc[3][2] += av.w * bv.z; acc[3][3] += av.w * bv.w;
    }
    __syncthreads();
  }
#pragma unroll
  for (int i = 0; i < 4; ++i)
#pragma unroll
    for (int j = 0; j < 4; ++j) {
      const int m = m0 + (ty << 2) + i, n = n0 + (tx << 2) + j;
      Z[(size_t)m * NGATE + (((n & 255) << 2) | (n >> 8))] = acc[i][j] + Bv[n];
    }
}

// ---------------------------------------------------------------------------
// Kernel 3: persistent bidirectional LSTM recurrence — all-MFMA, one WG per
// direction, WAVE-LOCAL GATES (R9).
//
// R8 post-mortem: redistributing the LDS frag stream worked (58% per-CU
// MfmaUtil) but the step still paid: zbuf4 write + barrier + read (with 786K
// bank conflicts from the transposed scatter) and a half-idle gate phase.
// R9 structural fix: wave w owns ALL FOUR GATES of its 32 units —
//   tile T = gate*2 + half (T=0..7), n = (T>>1)*256 + 32w + (T&1)*16 + lcol.
// Because the A-frag is REPLICATED across rows, acc[T][0] is valid on EVERY
// lane, so after the MFMA phase each lane holds z for all 4 gates of units
// u0=32w+lcol and u1=u0+16 IN REGISTERS: no z exchange, no zbuf4, no first
// barrier, no bank conflicts. Gate math runs on all 64 lanes (redundant x4
// across lq — redundancy is free; exchange isn't). h16 packs via the
// verified 0xB1 neighbor swap (l^1 == lcol^1); lq==0 even-lcol lanes write.
// ONE barrier/step; h16u parity dbuf makes it race-free (step s reads par
// before barrier(s); step s+1 writes par only after barrier(s)).
//
// Frags: 45 reg (bregA[8][5] T=0..4 + bregB[5] T=5,kc<5) + 19 LDS/wave
// (T=6,7 all kc; T=5 kc>=5), evenly spread so each kc iteration's 5-6 reg
// MFMAs cover its 2-3 ds_read_b128 (R8-proven). ~250 unified regs (clean).
// MFMA pipe floor 2483 cy/step; R8 measured 3515; target ~3100.
// ---------------------------------------------------------------------------
__global__ __launch_bounds__(512) __attribute__((amdgpu_waves_per_eu(2, 2)))
void recurrence(
    const float* __restrict__ whh_f, const float* __restrict__ whh_b,
    const float* __restrict__ h0, const float* __restrict__ c0,
    const float* __restrict__ ZX, float* __restrict__ HALL) {
  const int dir = blockIdx.x;
  const int t = threadIdx.x;
  const int w = t >> 6;            // wave 0..7
  const int l = t & 63;
  const int lcol = l & 15;
  const int lq = l >> 4;           // quadrant 0..3
  const float* __restrict__ Whh = dir ? whh_b : whh_f;
  const float* __restrict__ Z = ZX + (size_t)dir * LL * NGATE;
  float* __restrict__ Hall = HALL + (size_t)dir * LL * HH;

  __shared__ uint4 WL[8 * 19 * 64];                 // 152 KB LDS B-frags
  __shared__ __align__(16) unsigned h16u[2 * 128];  // packed f16 h, parity dbuf

  // ---- preamble: build B-frags (f32 -> f16 RTZ) --------------------------
  // tile T = gate*2 + half; n = (T>>1)*256 + (w<<5) + ((T&1)<<4) + lcol
  // reg: T<5 -> bregA[kc][T]; T==5,kc<5 -> bregB[kc]
  // LDS: T==6 -> id 2kc; T==7 -> id 2kc+1; T==5,kc>=5 -> id 16+(kc-5)
  v8h bregA[8][5];
  v8h bregB[5];
#pragma unroll
  for (int kc = 0; kc < 8; ++kc) {
#pragma unroll
    for (int T = 0; T < 8; ++T) {
      const int n = ((T >> 1) << 8) + (w << 5) + ((T & 1) << 4) + lcol;
      const float* wp = Whh + (size_t)n * HH + (kc << 5) + (lq << 3);
      const float4 a4 = *reinterpret_cast<const float4*>(wp);
      const float4 b4 = *reinterpret_cast<const float4*>(wp + 4);
      const v8h f = make_v8h(pack_h2(a4.x, a4.y), pack_h2(a4.z, a4.w),
                             pack_h2(b4.x, b4.y), pack_h2(b4.z, b4.w));
      if (T < 5) {
        bregA[kc][T] = f;
      } else if (T == 5) {
        if (kc < 5) bregB[kc] = f;
        else WL[(w * 19 + 16 + (kc - 5)) * 64 + l] = __builtin_bit_cast(uint4, f);
      } else {
        WL[(w * 19 + 2 * kc + (T - 6)) * 64 + l] = __builtin_bit_cast(uint4, f);
      }
    }
  }

  // ---- state init --------------------------------------------------------
  const int u0 = (w << 5) + lcol;   // half-0 unit of this lane
  const int u1 = u0 + 16;           // half-1 unit
  float c0r = c0[dir * HH + u0];    // redundant across lq (free)
  float c1r = c0[dir * HH + u1];
  if (t < 128)
    h16u[t] = pack_u(h0[dir * HH + 2 * t], h0[dir * HH + 2 * t + 1]);

  const int trow0 = dir ? (LL - 1) : 0;
  float4 zxA = *reinterpret_cast<const float4*>(Z + (size_t)trow0 * NGATE + 4 * u0);
  float4 zxB = *reinterpret_cast<const float4*>(Z + (size_t)trow0 * NGATE + 4 * u1);
  __syncthreads();

  const char* h16b = reinterpret_cast<const char*>(h16u);

  for (int s = 0; s < LL; ++s) {
    const int par = s & 1;
    const int npar = par ^ 1;
    // prefetch next step's Zx (hides under the matvec)
    float4 nzxA = make_float4(0.f, 0.f, 0.f, 0.f), nzxB = nzxA;
    if (s + 1 < LL) {
      const int trow = dir ? (LL - 2 - s) : (s + 1);
      nzxA = *reinterpret_cast<const float4*>(Z + (size_t)trow * NGATE + 4 * u0);
      nzxB = *reinterpret_cast<const float4*>(Z + (size_t)trow * NGATE + 4 * u1);
    }

    const uint4* hq = reinterpret_cast<const uint4*>(h16b + (par << 9));

    // ---- MFMA phase ------------------------------------------------------
    v4f acc0 = {0.f,0.f,0.f,0.f}, acc1 = {0.f,0.f,0.f,0.f};
    v4f acc2 = {0.f,0.f,0.f,0.f}, acc3 = {0.f,0.f,0.f,0.f};
    v4f acc4 = {0.f,0.f,0.f,0.f}, acc5 = {0.f,0.f,0.f,0.f};
    v4f acc6 = {0.f,0.f,0.f,0.f}, acc7 = {0.f,0.f,0.f,0.f};
#pragma unroll
    for (int kc = 0; kc < 8; ++kc) {
      const uint4 u6 = WL[(w * 19 + 2 * kc + 0) * 64 + l];
      const uint4 u7 = WL[(w * 19 + 2 * kc + 1) * 64 + l];
      uint4 u5;
      if (kc >= 5) u5 = WL[(w * 19 + 16 + (kc - 5)) * 64 + l];
      const v8h ah = __builtin_bit_cast(v8h, hq[(kc << 2) + lq]);
      acc0 = __builtin_amdgcn_mfma_f32_16x16x32_f16(ah, bregA[kc][0], acc0, 0, 0, 0);
      acc1 = __builtin_amdgcn_mfma_f32_16x16x32_f16(ah, bregA[kc][1], acc1, 0, 0, 0);
      acc2 = __builtin_amdgcn_mfma_f32_16x16x32_f16(ah, bregA[kc][2], acc2, 0, 0, 0);
      acc3 = __builtin_amdgcn_mfma_f32_16x16x32_f16(ah, bregA[kc][3], acc3, 0, 0, 0);
      acc4 = __builtin_amdgcn_mfma_f32_16x16x32_f16(ah, bregA[kc][4], acc4, 0, 0, 0);
      if (kc < 5)
        acc5 = __builtin_amdgcn_mfma_f32_16x16x32_f16(ah, bregB[kc], acc5, 0, 0, 0);
      else
        acc5 = __builtin_amdgcn_mfma_f32_16x16x32_f16(ah, __builtin_bit_cast(v8h, u5), acc5, 0, 0, 0);
      acc6 = __builtin_amdgcn_mfma_f32_16x16x32_f16(ah, __builtin_bit_cast(v8h, u6), acc6, 0, 0, 0);
      acc7 = __builtin_amdgcn_mfma_f32_16x16x32_f16(ah, __builtin_bit_cast(v8h, u7), acc7, 0, 0, 0);
    }

    // ---- wave-local gate phase (all lanes; redundant across lq) ----------
    // half 0 (unit u0): gates i,f,g,o = tiles 0,2,4,6
    const float zi0 = zxA.x + acc0[0];
    const float zf0 = zxA.y + acc2[0];
    const float zg0 = zxA.z + acc4[0];
    const float zo0 = zxA.w + acc6[0];
    const float i0 = fsigmoid(zi0), f0 = fsigmoid(zf0);
    const float g0 = ftanh(zg0),    o0 = fsigmoid(zo0);
    c0r = f0 * c0r + i0 * g0;
    const float h0v = o0 * ftanh(c0r);
    // half 1 (unit u1): tiles 1,3,5,7
    const float zi1 = zxB.x + acc1[0];
    const float zf1 = zxB.y + acc3[0];
    const float zg1 = zxB.z + acc5[0];
    const float zo1 = zxB.w + acc7[0];
    const float i1 = fsigmoid(zi1), f1 = fsigmoid(zf1);
    const float g1 = ftanh(zg1),    o1 = fsigmoid(zo1);
    c1r = f1 * c1r + i1 * g1;
    const float h1v = o1 * ftanh(c1r);

    const int trow = dir ? (LL - 1 - s) : s;
    if (lq == 0) {
      Hall[(size_t)trow * HH + u0] = h0v;
      Hall[(size_t)trow * HH + u1] = h1v;
    }
    // pack (h[2i], h[2i+1]) via lcol^1 neighbor swap (l^1 within quad)
    const float nb0 = dpp_f<0xB1>(h0v);
    const float nb1 = dpp_f<0xB1>(h1v);
    if (lq == 0 && (lcol & 1) == 0) {
      h16u[(npar << 7) + (w << 4) + (lcol >> 1)]     = pack_u(h0v, nb0);
      h16u[(npar << 7) + (w << 4) + 8 + (lcol >> 1)] = pack_u(h1v, nb1);
    }
    __syncthreads();
    zxA = nzxA; zxB = nzxB;
  }
}

// ---------------------------------------------------------------------------
// Kernel 4: feats
// ---------------------------------------------------------------------------
__global__ __launch_bounds__(256) void feats_gemm(
    const float* __restrict__ HALL, const float* __restrict__ Wout,
    const float* __restrict__ bout, float* __restrict__ FE) {
  __shared__ float Wl[16][516];
  const int t = threadIdx.x;
  for (int i = t; i < 16 * 512; i += 256) Wl[i >> 9][i & 511] = Wout[i];
  __syncthreads();
  const int row = blockIdx.x * 16 + (t >> 4);
  const int j = t & 15;
  const float* hf = HALL + (size_t)row * HH;
  const float* hb = HALL + (size_t)LL * HH + (size_t)row * HH;
  float acc = bout[j];
  for (int k = 0; k < HH; k += 4) {
    const float4 a = *reinterpret_cast<const float4*>(hf + k);
    const float4 wa = *reinterpret_cast<const float4*>(&Wl[j][k]);
    acc += a.x * wa.x + a.y * wa.y + a.z * wa.z + a.w * wa.w;
    const float4 b2 = *reinterpret_cast<const float4*>(hb + k);
    const float4 wb = *reinterpret_cast<const float4*>(&Wl[j][256 + k]);
    acc += b2.x * wb.x + b2.y * wb.y + b2.z * wb.z + b2.w * wb.w;
  }
  FE[(size_t)row * TT + j] = acc;
}

// ---------------------------------------------------------------------------
// Kernel 5: Viterbi (unchanged)
// ---------------------------------------------------------------------------
__global__ __launch_bounds__(1024) void viterbi(
    const float* __restrict__ FE, const float* __restrict__ trans,
    float* __restrict__ out) {
  __shared__ unsigned char bp8[LL * TT];
  __shared__ unsigned char xc[64 * 16];
  __shared__ unsigned char entry[64];
  __shared__ int sbest;
  const int t = threadIdx.x;

  if (t < 64) {
    const int n = t >> 2, pg = t & 3;
    const float tr0 = trans[n * 16 + (pg << 2) + 0];
    const float tr1 = trans[n * 16 + (pg << 2) + 1];
    const float tr2 = trans[n * 16 + (pg << 2) + 2];
    const float tr3 = trans[n * 16 + (pg << 2) + 3];
    float fvp0 = ((pg << 2) + 0 == 14) ? 0.f : NEGV;
    float fvp1 = ((pg << 2) + 1 == 14) ? 0.f : NEGV;
    float fvp2 = ((pg << 2) + 2 == 14) ? 0.f : NEGV;
    float fvp3 = ((pg << 2) + 3 == 14) ? 0.f : NEGV;

    auto step = [&](int s, float feat) {
      float bv = fvp0 + tr0; int bi = (pg << 2);
      float c;
      c = fvp1 + tr1; if (c > bv) { bv = c; bi = (pg << 2) + 1; }
      c = fvp2 + tr2; if (c > bv) { bv = c; bi = (pg << 2) + 2; }
      c = fvp3 + tr3; if (c > bv) { bv = c; bi = (pg << 2) + 3; }
      float pv = dpp_f<0xB1>(bv); int pi = dpp_i<0xB1>(bi);
      if (pv > bv || (pv == bv && pi < bi)) { bv = pv; bi = pi; }
      pv = dpp_f<0x4E>(bv); pi = dpp_i<0x4E>(bi);
      if (pv > bv || (pv == bv && pi < bi)) { bv = pv; bi = pi; }
      if (pg == 0) bp8[(s << 4) + n] = (unsigned char)bi;
      const float fvn = bv + feat;
      fvp0 = bperm_f((pg << 4) + 0,  fvn);
      fvp1 = bperm_f((pg << 4) + 4,  fvn);
      fvp2 = bperm_f((pg << 4) + 8,  fvn);
      fvp3 = bperm_f((pg << 4) + 12, fvn);
    };

    float fb0 = FE[(0 << 4) + n], fb1 = FE[(1 << 4) + n];
    float fb2 = FE[(2 << 4) + n], fb3 = FE[(3 << 4) + n];
    for (int s = 0; s < LL; s += 4) {
      step(s + 0, fb0); fb0 = (s + 4 < LL) ? FE[((s + 4) << 4) + n] : 0.f;
      step(s + 1, fb1); fb1 = (s + 5 < LL) ? FE[((s + 5) << 4) + n] : 0.f;
      step(s + 2, fb2); fb2 = (s + 6 < LL) ? FE[((s + 6) << 4) + n] : 0.f;
      step(s + 3, fb3); fb3 = (s + 7 < LL) ? FE[((s + 7) << 4) + n] : 0.f;
    }

    const float tt0 = trans[240 + (pg << 2) + 0];
    const float tt1 = trans[240 + (pg << 2) + 1];
    const float tt2 = trans[240 + (pg << 2) + 2];
    const float tt3 = trans[240 + (pg << 2) + 3];
    float bv = fvp0 + tt0; int bi = (pg << 2);
    float c;
    c = fvp1 + tt1; if (c > bv) { bv = c; bi = (pg << 2) + 1; }
    c = fvp2 + tt2; if (c > bv) { bv = c; bi = (pg << 2) + 2; }
    c = fvp3 + tt3; if (c > bv) { bv = c; bi = (pg << 2) + 3; }
    float pv = dpp_f<0xB1>(bv); int pi = dpp_i<0xB1>(bi);
    if (pv > bv || (pv == bv && pi < bi)) { bv = pv; bi = pi; }
    pv = dpp_f<0x4E>(bv); pi = dpp_i<0x4E>(bi);
    if (pv > bv || (pv == bv && pi < bi)) { bv = pv; bi = pi; }
    if (t == 0) { out[0] = bv; sbest = bi; }
  }
  __syncthreads();

  {
    const int c = t >> 4, e = t & 15;
    int tag = e;
#pragma unroll 1
    for (int i = 63; i >= 0; --i) tag = bp8[(((c << 6) + i) << 4) + tag];
    xc[(c << 4) + e] = (unsigned char)tag;
  }
  __syncthreads();
  if (t == 0) {
    int carry = sbest;
#pragma unroll 1
    for (int c = 63; c >= 0; --c) {
      entry[c] = (unsigned char)carry;
      carry = xc[(c << 4) + carry];
    }
  }
  __syncthreads();
  if (t < 64) {
    const int c = t;
    int tag = entry[c];
#pragma unroll 1
    for (int i = 63; i >= 0; --i) {
      const int s = (c << 6) + i;
      out[1 + s] = (float)tag;
      tag = bp8[(s << 4) + tag];
    }
  }
}

// ---------------------------------------------------------------------------
extern "C" void kernel_launch(void* const* d_in, const int* in_sizes, int n_in,
                              void* d_out, int out_size, void* d_ws, size_t ws_size,
                              hipStream_t stream) {
  const int*   sent = (const int*)d_in[0];
  const float* emb  = (const float*)d_in[1];
  const float* wihf = (const float*)d_in[2];
  const float* whhf = (const float*)d_in[3];
  const float* bf   = (const float*)d_in[4];
  const float* wihb = (const float*)d_in[5];
  const float* whhb = (const float*)d_in[6];
  const float* bb   = (const float*)d_in[7];
  const float* wout = (const float*)d_in[8];
  const float* bout = (const float*)d_in[9];
  const float* trans= (const float*)d_in[10];
  const float* h0   = (const float*)d_in[11];
  const float* c0   = (const float*)d_in[12];
  float* out = (float*)d_out;
  char* ws = (char*)d_ws;

  float* X    = (float*)(ws + OFF_X);
  float* ZX   = (float*)(ws + OFF_ZX);
  float* HALL = (float*)(ws + OFF_HALL);
  float* FE   = (float*)(ws + OFF_FE);

  gather_x<<<(LL * (EE / 4) + 255) / 256, 256, 0, stream>>>(sent, emb, X);
  input_gemm<<<dim3(16, 64, 2), 256, 0, stream>>>(X, wihf, bf, wihb, bb, ZX);
  recurrence<<<2, 512, 0, stream>>>(whhf, whhb, h0, c0, ZX, HALL);
  feats_gemm<<<LL / 16, 256, 0, stream>>>(HALL, wout, bout, FE);
  viterbi<<<1, 1024, 0, stream>>>(FE, trans, out);
}

// Round 10
// 6275.474 us; speedup vs baseline: 1.6989x; 1.0315x over previous
//
#include <hip/hip_runtime.h>
#include <math.h>
#include <stdint.h>

// Problem constants
constexpr int LL = 4096;   // seq len
constexpr int EE = 300;    // embedding dim
constexpr int HH = 256;    // per-direction hidden (H2)
constexpr int NGATE = 1024;// 4*HH
constexpr int TT = 16;     // tagset
constexpr float NEGV = -10000.0f;

typedef _Float16 v2h __attribute__((ext_vector_type(2)));
typedef _Float16 v8h __attribute__((ext_vector_type(8)));
typedef float v4f __attribute__((ext_vector_type(4)));

// Workspace layout (byte offsets)
constexpr size_t OFF_X    = 16384;
constexpr size_t OFF_ZX   = OFF_X    + (size_t)LL*EE*4;     // 2*L*1024 f32
constexpr size_t OFF_HALL = OFF_ZX   + (size_t)2*LL*NGATE*4;// 2*L*256 f32
constexpr size_t OFF_FE   = OFF_HALL + (size_t)2*LL*HH*4;   // L*16 f32

__device__ __forceinline__ v2h pack_h2(float x, float y) {
  return __builtin_bit_cast(v2h, __builtin_amdgcn_cvt_pkrtz(x, y));
}
__device__ __forceinline__ unsigned pack_u(float x, float y) {
  return __builtin_bit_cast(unsigned, __builtin_amdgcn_cvt_pkrtz(x, y));
}
__device__ __forceinline__ v8h make_v8h(v2h a, v2h b, v2h c, v2h d) {
  union { v2h p[4]; v8h v; } u; u.p[0]=a; u.p[1]=b; u.p[2]=c; u.p[3]=d; return u.v;
}

__device__ __forceinline__ float fsigmoid(float x) {
  return __builtin_amdgcn_rcpf(1.f + __expf(-x));
}
__device__ __forceinline__ float ftanh(float x) {
  return 1.f - 2.f * __builtin_amdgcn_rcpf(1.f + __expf(2.f * x));
}

template <int CTRL>
__device__ __forceinline__ int dpp_i(int v) {
  return __builtin_amdgcn_mov_dpp(v, CTRL, 0xF, 0xF, true);
}
template <int CTRL>
__device__ __forceinline__ float dpp_f(float v) {
  return __int_as_float(__builtin_amdgcn_mov_dpp(__float_as_int(v), CTRL, 0xF, 0xF, true));
}
__device__ __forceinline__ float bperm_f(int lane, float v) {
  return __int_as_float(__builtin_amdgcn_ds_bpermute(lane << 2, __float_as_int(v)));
}

// ---------------------------------------------------------------------------
// Kernel 1: embedding gather
// ---------------------------------------------------------------------------
__global__ void gather_x(const int* __restrict__ sent, const float* __restrict__ emb,
                         float* __restrict__ X) {
  const int i = blockIdx.x * blockDim.x + threadIdx.x;
  const int total = LL * (EE / 4);
  if (i >= total) return;
  const int row = i / (EE / 4), c4 = i % (EE / 4);
  const int v = sent[row];
  reinterpret_cast<float4*>(X)[(size_t)row * (EE / 4) + c4] =
      reinterpret_cast<const float4*>(emb + (size_t)v * EE)[c4];
}

// ---------------------------------------------------------------------------
// Kernel 2: input GEMM, GATE-TRANSPOSED store: Zx[t][unit*4+gate]
// (unchanged — validated R5-R9)
// ---------------------------------------------------------------------------
__global__ __launch_bounds__(256) void input_gemm(
    const float* __restrict__ X, const float* __restrict__ w_f,
    const float* __restrict__ b_f, const float* __restrict__ w_b,
    const float* __restrict__ b_b, float* __restrict__ ZX) {
  const int dir = blockIdx.z;
  const float* __restrict__ W  = dir ? w_b : w_f;
  const float* __restrict__ Bv = dir ? b_b : b_f;
  float* __restrict__ Z = ZX + (size_t)dir * LL * NGATE;
  __shared__ float As[32][68];
  __shared__ float Bs[32][68];
  const int m0 = blockIdx.y * 64, n0 = blockIdx.x * 64;
  const int t = threadIdx.x;
  const int tx = t & 15, ty = t >> 4;
  float acc[4][4] = {};
  for (int k0 = 0; k0 < EE; k0 += 32) {
#pragma unroll
    for (int r = 0; r < 2; ++r) {
      const int idx = t + r * 256;
      const int row = idx >> 3;
      const int kk4 = (idx & 7) << 2;
      const int k = k0 + kk4;
      float4 va = make_float4(0.f, 0.f, 0.f, 0.f), vb = va;
      if (k < EE) {
        va = *reinterpret_cast<const float4*>(X + (size_t)(m0 + row) * EE + k);
        vb = *reinterpret_cast<const float4*>(W + (size_t)(n0 + row) * EE + k);
      }
      As[kk4 + 0][row] = va.x; As[kk4 + 1][row] = va.y;
      As[kk4 + 2][row] = va.z; As[kk4 + 3][row] = va.w;
      Bs[kk4 + 0][row] = vb.x; Bs[kk4 + 1][row] = vb.y;
      Bs[kk4 + 2][row] = vb.z; Bs[kk4 + 3][row] = vb.w;
    }
    __syncthreads();
    const int kmax = (EE - k0 < 32) ? (EE - k0) : 32;
    for (int k = 0; k < kmax; ++k) {
      const float4 av = *reinterpret_cast<const float4*>(&As[k][ty << 2]);
      const float4 bv = *reinterpret_cast<const float4*>(&Bs[k][tx << 2]);
      acc[0][0] += av.x * bv.x; acc[0][1] += av.x * bv.y; acc[0][2] += av.x * bv.z; acc[0][3] += av.x * bv.w;
      acc[1][0] += av.y * bv.x; acc[1][1] += av.y * bv.y; acc[1][2] += av.y * bv.z; acc[1][3] += av.y * bv.w;
      acc[2][0] += av.z * bv.x; acc[2][1] += av.z * bv.y; acc[2][2] += av.z * bv.z; acc[2][3] += av.z * bv.w;
      acc[3][0] += av.w * bv.x; acc[3][1] += av.w * bv.y; acc[3][2] += av.w * bv.z; acc[3][3] += av.w * bv.w;
    }
    __syncthreads();
  }
#pragma unroll
  for (int i = 0; i < 4; ++i)
#pragma unroll
    for (int j = 0; j < 4; ++j) {
      const int m = m0 + (ty << 2) + i, n = n0 + (tx << 2) + j;
      Z[(size_t)m * NGATE + (((n & 255) << 2) | (n >> 8))] = acc[i][j] + Bv[n];
    }
}

// ---------------------------------------------------------------------------
// Kernel 3: persistent bidirectional LSTM recurrence — all-MFMA, one WG per
// direction, wave-local gates (R9) + LQ-SPLIT GATES (R10).
//
// R9 post-mortem: zbuf4/barrier removal worked (64% per-CU MfmaUtil, 0 bank
// conflicts) but the x4-redundant gate phase runs barrier-locked on BOTH
// waves of each SIMD -> ~1240 cy/step of VALU issue with the MFMA pipe idle.
// R10: lanes lq in {0,1} compute only half-0 (unit u=32w+lcol), lq in {2,3}
// only half-1 (u=32w+16+lcol) — acc selection via cndmask. Gate issue and
// Zx loads halve. Writers: (lq&1)==0 lanes store Hall[u]; even-lcol among
// them write the h16 pack (0xB1 neighbor swap stays within quad+half).
// Zx/Hall use running pointers (+-NGATE/+-HH per step, no trow multiply, no
// end-guard: the one-past prefetch lands in the adjacent direction's valid
// workspace rows — read, never used).
//
// Frags (R8/R9-proven): 45 reg (bregA[8][5] T=0..4 + bregB[5] T=5,kc<5) +
// 19 LDS/wave spread evenly so each kc's 5-6 reg MFMAs cover its 2-3
// ds_read_b128. ONE barrier/step; h16u parity dbuf race-free.
// MFMA floor 2483 cy + ~120 cy h-read latency; R9 measured 3176; target
// ~2900.
// ---------------------------------------------------------------------------
__global__ __launch_bounds__(512) __attribute__((amdgpu_waves_per_eu(2, 2)))
void recurrence(
    const float* __restrict__ whh_f, const float* __restrict__ whh_b,
    const float* __restrict__ h0, const float* __restrict__ c0,
    const float* __restrict__ ZX, float* __restrict__ HALL) {
  const int dir = blockIdx.x;
  const int t = threadIdx.x;
  const int w = t >> 6;            // wave 0..7
  const int l = t & 63;
  const int lcol = l & 15;
  const int lq = l >> 4;           // quadrant 0..3
  const bool hi = (lq >= 2);       // this lane's half
  const int u = (w << 5) + (hi ? 16 : 0) + lcol;   // this lane's unit
  const float* __restrict__ Whh = dir ? whh_b : whh_f;
  const float* __restrict__ Z = ZX + (size_t)dir * LL * NGATE;
  float* __restrict__ Hall = HALL + (size_t)dir * LL * HH;

  __shared__ uint4 WL[8 * 19 * 64];                 // 152 KB LDS B-frags
  __shared__ __align__(16) unsigned h16u[2 * 128];  // packed f16 h, parity dbuf

  // ---- preamble: build B-frags (f32 -> f16 RTZ) --------------------------
  // tile T = gate*2 + half; n = (T>>1)*256 + (w<<5) + ((T&1)<<4) + lcol
  // reg: T<5 -> bregA[kc][T]; T==5,kc<5 -> bregB[kc]
  // LDS: T==6 -> id 2kc; T==7 -> id 2kc+1; T==5,kc>=5 -> id 16+(kc-5)
  v8h bregA[8][5];
  v8h bregB[5];
#pragma unroll
  for (int kc = 0; kc < 8; ++kc) {
#pragma unroll
    for (int T = 0; T < 8; ++T) {
      const int n = ((T >> 1) << 8) + (w << 5) + ((T & 1) << 4) + lcol;
      const float* wp = Whh + (size_t)n * HH + (kc << 5) + (lq << 3);
      const float4 a4 = *reinterpret_cast<const float4*>(wp);
      const float4 b4 = *reinterpret_cast<const float4*>(wp + 4);
      const v8h f = make_v8h(pack_h2(a4.x, a4.y), pack_h2(a4.z, a4.w),
                             pack_h2(b4.x, b4.y), pack_h2(b4.z, b4.w));
      if (T < 5) {
        bregA[kc][T] = f;
      } else if (T == 5) {
        if (kc < 5) bregB[kc] = f;
        else WL[(w * 19 + 16 + (kc - 5)) * 64 + l] = __builtin_bit_cast(uint4, f);
      } else {
        WL[(w * 19 + 2 * kc + (T - 6)) * 64 + l] = __builtin_bit_cast(uint4, f);
      }
    }
  }

  // ---- state init --------------------------------------------------------
  float c_reg = c0[dir * HH + u];       // per-lane half state
  if (t < 128)
    h16u[t] = pack_u(h0[dir * HH + 2 * t], h0[dir * HH + 2 * t + 1]);

  // running row pointers (walk instead of per-step multiply)
  const int zstride = dir ? -NGATE : NGATE;
  const int hstride = dir ? -HH : HH;
  const float* zrow = Z + (size_t)(dir ? (LL - 1) : 0) * NGATE;
  float* hrow = Hall + (size_t)(dir ? (LL - 1) : 0) * HH;

  float4 zx = *reinterpret_cast<const float4*>(zrow + 4 * u);
  __syncthreads();

  const char* h16b = reinterpret_cast<const char*>(h16u);

  for (int s = 0; s < LL; ++s) {
    const int par = s & 1;
    const int npar = par ^ 1;
    // prefetch next step's Zx (unconditional pointer walk; final over-read
    // lands in the adjacent direction's valid rows and is never used)
    zrow += zstride;
    const float4 nzx = *reinterpret_cast<const float4*>(zrow + 4 * u);

    const uint4* hq = reinterpret_cast<const uint4*>(h16b + (par << 9));

    // ---- MFMA phase ------------------------------------------------------
    v4f acc0 = {0.f,0.f,0.f,0.f}, acc1 = {0.f,0.f,0.f,0.f};
    v4f acc2 = {0.f,0.f,0.f,0.f}, acc3 = {0.f,0.f,0.f,0.f};
    v4f acc4 = {0.f,0.f,0.f,0.f}, acc5 = {0.f,0.f,0.f,0.f};
    v4f acc6 = {0.f,0.f,0.f,0.f}, acc7 = {0.f,0.f,0.f,0.f};
#pragma unroll
    for (int kc = 0; kc < 8; ++kc) {
      const uint4 u6 = WL[(w * 19 + 2 * kc + 0) * 64 + l];
      const uint4 u7 = WL[(w * 19 + 2 * kc + 1) * 64 + l];
      uint4 u5;
      if (kc >= 5) u5 = WL[(w * 19 + 16 + (kc - 5)) * 64 + l];
      const v8h ah = __builtin_bit_cast(v8h, hq[(kc << 2) + lq]);
      acc0 = __builtin_amdgcn_mfma_f32_16x16x32_f16(ah, bregA[kc][0], acc0, 0, 0, 0);
      acc1 = __builtin_amdgcn_mfma_f32_16x16x32_f16(ah, bregA[kc][1], acc1, 0, 0, 0);
      acc2 = __builtin_amdgcn_mfma_f32_16x16x32_f16(ah, bregA[kc][2], acc2, 0, 0, 0);
      acc3 = __builtin_amdgcn_mfma_f32_16x16x32_f16(ah, bregA[kc][3], acc3, 0, 0, 0);
      acc4 = __builtin_amdgcn_mfma_f32_16x16x32_f16(ah, bregA[kc][4], acc4, 0, 0, 0);
      if (kc < 5)
        acc5 = __builtin_amdgcn_mfma_f32_16x16x32_f16(ah, bregB[kc], acc5, 0, 0, 0);
      else
        acc5 = __builtin_amdgcn_mfma_f32_16x16x32_f16(ah, __builtin_bit_cast(v8h, u5), acc5, 0, 0, 0);
      acc6 = __builtin_amdgcn_mfma_f32_16x16x32_f16(ah, __builtin_bit_cast(v8h, u6), acc6, 0, 0, 0);
      acc7 = __builtin_amdgcn_mfma_f32_16x16x32_f16(ah, __builtin_bit_cast(v8h, u7), acc7, 0, 0, 0);
    }

    // ---- lq-split gate phase: this lane computes ONE unit ----------------
    // half0 (lq<2): gates = tiles 0,2,4,6 ; half1 (lq>=2): tiles 1,3,5,7
    const float zi = zx.x + (hi ? acc1[0] : acc0[0]);
    const float zf = zx.y + (hi ? acc3[0] : acc2[0]);
    const float zg = zx.z + (hi ? acc5[0] : acc4[0]);
    const float zo = zx.w + (hi ? acc7[0] : acc6[0]);
    const float ig = fsigmoid(zi);
    const float fg = fsigmoid(zf);
    const float gg = ftanh(zg);
    const float og = fsigmoid(zo);
    c_reg = fg * c_reg + ig * gg;
    const float hval = og * ftanh(c_reg);

    if ((lq & 1) == 0) hrow[u] = hval;           // lq 0 stores u0, lq 2 stores u1
    // pack (h[2i], h[2i+1]) via lcol^1 neighbor swap (l^1 within quad+half)
    const float nb = dpp_f<0xB1>(hval);
    if ((lq & 1) == 0 && (lcol & 1) == 0)
      h16u[(npar << 7) + (w << 4) + (hi ? 8 : 0) + (lcol >> 1)] = pack_u(hval, nb);
    __syncthreads();
    zx = nzx;
    hrow += hstride;
  }
}

// ---------------------------------------------------------------------------
// Kernel 4: feats
// ---------------------------------------------------------------------------
__global__ __launch_bounds__(256) void feats_gemm(
    const float* __restrict__ HALL, const float* __restrict__ Wout,
    const float* __restrict__ bout, float* __restrict__ FE) {
  __shared__ float Wl[16][516];
  const int t = threadIdx.x;
  for (int i = t; i < 16 * 512; i += 256) Wl[i >> 9][i & 511] = Wout[i];
  __syncthreads();
  const int row = blockIdx.x * 16 + (t >> 4);
  const int j = t & 15;
  const float* hf = HALL + (size_t)row * HH;
  const float* hb = HALL + (size_t)LL * HH + (size_t)row * HH;
  float acc = bout[j];
  for (int k = 0; k < HH; k += 4) {
    const float4 a = *reinterpret_cast<const float4*>(hf + k);
    const float4 wa = *reinterpret_cast<const float4*>(&Wl[j][k]);
    acc += a.x * wa.x + a.y * wa.y + a.z * wa.z + a.w * wa.w;
    const float4 b2 = *reinterpret_cast<const float4*>(hb + k);
    const float4 wb = *reinterpret_cast<const float4*>(&Wl[j][256 + k]);
    acc += b2.x * wb.x + b2.y * wb.y + b2.z * wb.z + b2.w * wb.w;
  }
  FE[(size_t)row * TT + j] = acc;
}

// ---------------------------------------------------------------------------
// Kernel 5: Viterbi (unchanged)
// ---------------------------------------------------------------------------
__global__ __launch_bounds__(1024) void viterbi(
    const float* __restrict__ FE, const float* __restrict__ trans,
    float* __restrict__ out) {
  __shared__ unsigned char bp8[LL * TT];
  __shared__ unsigned char xc[64 * 16];
  __shared__ unsigned char entry[64];
  __shared__ int sbest;
  const int t = threadIdx.x;

  if (t < 64) {
    const int n = t >> 2, pg = t & 3;
    const float tr0 = trans[n * 16 + (pg << 2) + 0];
    const float tr1 = trans[n * 16 + (pg << 2) + 1];
    const float tr2 = trans[n * 16 + (pg << 2) + 2];
    const float tr3 = trans[n * 16 + (pg << 2) + 3];
    float fvp0 = ((pg << 2) + 0 == 14) ? 0.f : NEGV;
    float fvp1 = ((pg << 2) + 1 == 14) ? 0.f : NEGV;
    float fvp2 = ((pg << 2) + 2 == 14) ? 0.f : NEGV;
    float fvp3 = ((pg << 2) + 3 == 14) ? 0.f : NEGV;

    auto step = [&](int s, float feat) {
      float bv = fvp0 + tr0; int bi = (pg << 2);
      float c;
      c = fvp1 + tr1; if (c > bv) { bv = c; bi = (pg << 2) + 1; }
      c = fvp2 + tr2; if (c > bv) { bv = c; bi = (pg << 2) + 2; }
      c = fvp3 + tr3; if (c > bv) { bv = c; bi = (pg << 2) + 3; }
      float pv = dpp_f<0xB1>(bv); int pi = dpp_i<0xB1>(bi);
      if (pv > bv || (pv == bv && pi < bi)) { bv = pv; bi = pi; }
      pv = dpp_f<0x4E>(bv); pi = dpp_i<0x4E>(bi);
      if (pv > bv || (pv == bv && pi < bi)) { bv = pv; bi = pi; }
      if (pg == 0) bp8[(s << 4) + n] = (unsigned char)bi;
      const float fvn = bv + feat;
      fvp0 = bperm_f((pg << 4) + 0,  fvn);
      fvp1 = bperm_f((pg << 4) + 4,  fvn);
      fvp2 = bperm_f((pg << 4) + 8,  fvn);
      fvp3 = bperm_f((pg << 4) + 12, fvn);
    };

    float fb0 = FE[(0 << 4) + n], fb1 = FE[(1 << 4) + n];
    float fb2 = FE[(2 << 4) + n], fb3 = FE[(3 << 4) + n];
    for (int s = 0; s < LL; s += 4) {
      step(s + 0, fb0); fb0 = (s + 4 < LL) ? FE[((s + 4) << 4) + n] : 0.f;
      step(s + 1, fb1); fb1 = (s + 5 < LL) ? FE[((s + 5) << 4) + n] : 0.f;
      step(s + 2, fb2); fb2 = (s + 6 < LL) ? FE[((s + 6) << 4) + n] : 0.f;
      step(s + 3, fb3); fb3 = (s + 7 < LL) ? FE[((s + 7) << 4) + n] : 0.f;
    }

    const float tt0 = trans[240 + (pg << 2) + 0];
    const float tt1 = trans[240 + (pg << 2) + 1];
    const float tt2 = trans[240 + (pg << 2) + 2];
    const float tt3 = trans[240 + (pg << 2) + 3];
    float bv = fvp0 + tt0; int bi = (pg << 2);
    float c;
    c = fvp1 + tt1; if (c > bv) { bv = c; bi = (pg << 2) + 1; }
    c = fvp2 + tt2; if (c > bv) { bv = c; bi = (pg << 2) + 2; }
    c = fvp3 + tt3; if (c > bv) { bv = c; bi = (pg << 2) + 3; }
    float pv = dpp_f<0xB1>(bv); int pi = dpp_i<0xB1>(bi);
    if (pv > bv || (pv == bv && pi < bi)) { bv = pv; bi = pi; }
    pv = dpp_f<0x4E>(bv); pi = dpp_i<0x4E>(bi);
    if (pv > bv || (pv == bv && pi < bi)) { bv = pv; bi = pi; }
    if (t == 0) { out[0] = bv; sbest = bi; }
  }
  __syncthreads();

  {
    const int c = t >> 4, e = t & 15;
    int tag = e;
#pragma unroll 1
    for (int i = 63; i >= 0; --i) tag = bp8[(((c << 6) + i) << 4) + tag];
    xc[(c << 4) + e] = (unsigned char)tag;
  }
  __syncthreads();
  if (t == 0) {
    int carry = sbest;
#pragma unroll 1
    for (int c = 63; c >= 0; --c) {
      entry[c] = (unsigned char)carry;
      carry = xc[(c << 4) + carry];
    }
  }
  __syncthreads();
  if (t < 64) {
    const int c = t;
    int tag = entry[c];
#pragma unroll 1
    for (int i = 63; i >= 0; --i) {
      const int s = (c << 6) + i;
      out[1 + s] = (float)tag;
      tag = bp8[(s << 4) + tag];
    }
  }
}

// ---------------------------------------------------------------------------
extern "C" void kernel_launch(void* const* d_in, const int* in_sizes, int n_in,
                              void* d_out, int out_size, void* d_ws, size_t ws_size,
                              hipStream_t stream) {
  const int*   sent = (const int*)d_in[0];
  const float* emb  = (const float*)d_in[1];
  const float* wihf = (const float*)d_in[2];
  const float* whhf = (const float*)d_in[3];
  const float* bf   = (const float*)d_in[4];
  const float* wihb = (const float*)d_in[5];
  const float* whhb = (const float*)d_in[6];
  const float* bb   = (const float*)d_in[7];
  const float* wout = (const float*)d_in[8];
  const float* bout = (const float*)d_in[9];
  const float* trans= (const float*)d_in[10];
  const float* h0   = (const float*)d_in[11];
  const float* c0   = (const float*)d_in[12];
  float* out = (float*)d_out;
  char* ws = (char*)d_ws;

  float* X    = (float*)(ws + OFF_X);
  float* ZX   = (float*)(ws + OFF_ZX);
  float* HALL = (float*)(ws + OFF_HALL);
  float* FE   = (float*)(ws + OFF_FE);

  gather_x<<<(LL * (EE / 4) + 255) / 256, 256, 0, stream>>>(sent, emb, X);
  input_gemm<<<dim3(16, 64, 2), 256, 0, stream>>>(X, wihf, bf, wihb, bb, ZX);
  recurrence<<<2, 512, 0, stream>>>(whhf, whhb, h0, c0, ZX, HALL);
  feats_gemm<<<LL / 16, 256, 0, stream>>>(HALL, wout, bout, FE);
  viterbi<<<1, 1024, 0, stream>>>(FE, trans, out);
}